// Round 3
// baseline (325.314 us; speedup 1.0000x reference)
//
#include <hip/hip_runtime.h>
#include <hip/hip_bf16.h>

// B=1024, N=96/branch, D=512.
// h1[b,n,:] = relu(U[b] + e[b,n]*T[n] + b1);  U=img@W1[:512], T=text@W1[512:]
// m2[b] = mean_n relu(h1@W2 + b2);  out = m2@W3 + b3
// prep: sims/softmax/e + U gemm (f32) + T gemm (bf16) + W2^T bf16, one launch.
// branch_mlp3: barrier-free K-loop; h1 A-fragments built in registers, bf16 MFMA.

typedef __attribute__((ext_vector_type(8))) short short8;
typedef __attribute__((ext_vector_type(4))) float floatx4;

__device__ __forceinline__ unsigned short f2bf(float x) {
    unsigned int u = __float_as_uint(x);
    u += 0x7fffu + ((u >> 16) & 1u);   // RNE
    return (unsigned short)(u >> 16);
}
__device__ __forceinline__ float bf2f(unsigned short u) {
    return __uint_as_float(((unsigned int)u) << 16);
}

// ---- 16x64-tile fp32 GEMM (K=512): C[r0..r0+16)[c0..c0+64) = A @ B ------------
template <bool BF16OUT>
__device__ __forceinline__ void gemm16(
    const float* __restrict__ A0, const float* __restrict__ A1, int rows0,
    const float* __restrict__ Bm, float* __restrict__ Cf,
    unsigned short* __restrict__ Cb, int mt, int nt, float* sA /*16*33*/, int t) {
    int r0 = mt * 16, c0 = nt * 64;
    int row = t >> 4, cg = t & 15;
    int rglob = r0 + row;
    const float* Ap = (rglob < rows0) ? (A0 + rglob * 512) : (A1 + (rglob - rows0) * 512);
    float a0 = 0.f, a1 = 0.f, a2 = 0.f, a3 = 0.f;
    const float* Bp = Bm + c0 + cg * 4;
    for (int k0 = 0; k0 < 512; k0 += 32) {
        __syncthreads();
        float2 av = *(const float2*)(Ap + k0 + cg * 2);
        sA[row * 33 + cg * 2] = av.x;
        sA[row * 33 + cg * 2 + 1] = av.y;
        __syncthreads();
#pragma unroll 8
        for (int kk = 0; kk < 32; kk++) {
            float a = sA[row * 33 + kk];
            float4 bv = *(const float4*)(Bp + (k0 + kk) * 512);
            a0 = fmaf(a, bv.x, a0); a1 = fmaf(a, bv.y, a1);
            a2 = fmaf(a, bv.z, a2); a3 = fmaf(a, bv.w, a3);
        }
    }
    int c = c0 + cg * 4;
    if (BF16OUT) {
        unsigned long long pk =
            (unsigned long long)f2bf(a0) | ((unsigned long long)f2bf(a1) << 16) |
            ((unsigned long long)f2bf(a2) << 32) | ((unsigned long long)f2bf(a3) << 48);
        *(unsigned long long*)(Cb + rglob * 512 + c) = pk;
    } else {
        *(float4*)(Cf + rglob * 512 + c) = make_float4(a0, a1, a2, a3);
    }
}

// ---- prep: [0,1024) sims | [1024,1536) U gemm | [1536,1632) T gemm | [1632,1648) W2T
__global__ __launch_bounds__(256) void prep_kernel(
    const float* __restrict__ img, const float* __restrict__ tn,
    const float* __restrict__ ta, const float* __restrict__ ls,
    const float* __restrict__ W1, const float* __restrict__ W2,
    float* __restrict__ e_ws, float* __restrict__ U_ws,
    unsigned short* __restrict__ Tb, unsigned short* __restrict__ W2T) {
    __shared__ __align__(16) float smem[720];
    int idx = blockIdx.x;
    int t = threadIdx.x;

    if (idx < 1024) {
        int b = idx;
        float* sImg = smem;            // 512
        float* sS   = smem + 512;      // 192
        float* sMx  = smem + 704;      // 2
        float* sSum = smem + 706;      // 2
        for (int i = t; i < 512; i += 256) sImg[i] = img[b * 512 + i];
        __syncthreads();
        float scale = __expf(ls[0]);
        int g = t & 7;
#pragma unroll
        for (int i = 0; i < 6; i++) {
            int n = (t >> 3) + 32 * i;
            const float* tx = (n < 96) ? (tn + n * 512) : (ta + (n - 96) * 512);
            float d = 0.f;
#pragma unroll
            for (int s = 0; s < 16; s++) {
                int k = g * 4 + s * 32;
                float4 x = *(const float4*)(tx + k);
                d += x.x * sImg[k] + x.y * sImg[k + 1] + x.z * sImg[k + 2] + x.w * sImg[k + 3];
            }
            d += __shfl_xor(d, 1);
            d += __shfl_xor(d, 2);
            d += __shfl_xor(d, 4);
            if (g == 0) sS[n] = d * scale;
        }
        __syncthreads();
        if (t < 2) {
            float m = -1e30f;
            for (int n = 0; n < 96; n++) m = fmaxf(m, sS[t * 96 + n]);
            float s = 0.f;
            for (int n = 0; n < 96; n++) s += __expf(sS[t * 96 + n] - m);
            sMx[t] = m; sSum[t] = s;
        }
        __syncthreads();
        if (t < 192) {
            int br = t / 96, n = t % 96;
            float w = __expf(sS[t] - sMx[br]) / sSum[br];
            e_ws[(br * 1024 + b) * 96 + n] = __expf(w);
        }
    } else if (idx < 1536) {
        int i = idx - 1024;            // 64 mtiles x 8 ntiles
        gemm16<false>(img, img, 1 << 20, W1, U_ws, nullptr, i >> 3, i & 7, smem, t);
    } else if (idx < 1632) {
        int i = idx - 1536;            // 12 mtiles x 8 ntiles (192 rows: tn|ta)
        gemm16<true>(tn, ta, 96, W1 + 512 * 512, nullptr, Tb, i >> 3, i & 7, smem, t);
    } else {
        int i = idx - 1632;            // 16 blocks x 16 n-rows
        for (int r = 0; r < 16; r++) {
            int n = i * 16 + r;
            for (int k = t; k < 512; k += 256)
                W2T[n * 512 + k] = f2bf(W2[k * 256 + n]);
        }
    }
}

// ---- branch_mlp3: barrier-free fused h1 -> (h1@W2) -> relu -> mean -> @W3 ------
// grid (1024, 2), block 256 (4 waves). Wave w: cols [w*64, w*64+64), rows 96, K=512.
__global__ __launch_bounds__(256) void branch_mlp3(
    const float* __restrict__ U, const unsigned short* __restrict__ Tb,
    const float* __restrict__ e_all, const unsigned short* __restrict__ W2T,
    const float* __restrict__ b1, const float* __restrict__ b2,
    const float* __restrict__ W3, const float* __restrict__ b3,
    float* __restrict__ out) {
    int b = blockIdx.x, br = blockIdx.y;
    const unsigned short* T = Tb + br * (96 * 512);

    __shared__ float sUb[512];
    __shared__ float sE[96];
    __shared__ float sM2[256];
    __shared__ float sPart[256];

    int t = threadIdx.x;
    for (int i = t; i < 512; i += 256) sUb[i] = U[b * 512 + i] + b1[i];
    if (t < 96) sE[t] = e_all[(br * 1024 + b) * 96 + t];
    __syncthreads();

    const int wave = t >> 6, lane = t & 63;
    const int frow = lane & 15, fkq = (lane >> 4) * 8;
    const int ncol0 = wave * 64;

    float ev[6];
#pragma unroll
    for (int mt = 0; mt < 6; mt++) ev[mt] = sE[mt * 16 + frow];

    const floatx4 fz = {0.f, 0.f, 0.f, 0.f};
    floatx4 acc[6][4];
#pragma unroll
    for (int mt = 0; mt < 6; mt++)
#pragma unroll
        for (int j = 0; j < 4; j++) acc[mt][j] = fz;

    const unsigned short* Trow = T + frow * 512 + fkq;
    const unsigned short* Brow = W2T + (ncol0 + frow) * 512 + fkq;

#pragma unroll 2
    for (int s = 0; s < 16; s++) {
        int k0 = s * 32;
        float4 u0 = *(const float4*)(&sUb[k0 + fkq]);
        float4 u1 = *(const float4*)(&sUb[k0 + fkq + 4]);
        float ua[8] = {u0.x, u0.y, u0.z, u0.w, u1.x, u1.y, u1.z, u1.w};
        short8 bfr[4];
#pragma unroll
        for (int j = 0; j < 4; j++)
            bfr[j] = *(const short8*)(Brow + j * (16 * 512) + k0);
#pragma unroll
        for (int mt = 0; mt < 6; mt++) {
            short8 tv = *(const short8*)(Trow + mt * (16 * 512) + k0);
            short8 afr;
#pragma unroll
            for (int jj = 0; jj < 4; jj++) {
                float f0 = fmaxf(fmaf(ev[mt], bf2f((unsigned short)tv[2 * jj]), ua[2 * jj]), 0.f);
                float f1 = fmaxf(fmaf(ev[mt], bf2f((unsigned short)tv[2 * jj + 1]), ua[2 * jj + 1]), 0.f);
                __hip_bfloat162 h2 = __float22bfloat162_rn(make_float2(f0, f1));
                unsigned int bits;
                __builtin_memcpy(&bits, &h2, 4);
                ((unsigned int*)&afr)[jj] = bits;
            }
#pragma unroll
            for (int j = 0; j < 4; j++)
                acc[mt][j] = __builtin_amdgcn_mfma_f32_16x16x32_bf16(afr, bfr[j], acc[mt][j], 0, 0, 0);
        }
    }

    // epilogue 1: +b2, relu, mean over 96 rows -> sM2[256]
#pragma unroll
    for (int j = 0; j < 4; j++) {
        int col = ncol0 + j * 16 + frow;
        float bb = b2[col];
        float s = 0.f;
#pragma unroll
        for (int mt = 0; mt < 6; mt++)
#pragma unroll
            for (int r = 0; r < 4; r++)
                s += fmaxf(acc[mt][j][r] + bb, 0.f);
        s += __shfl_xor(s, 16);
        s += __shfl_xor(s, 32);
        if (lane < 16) sM2[col] = s * (1.0f / 96.0f);
    }
    __syncthreads();

    // epilogue 2: out = sM2 @ W3 + b3   (256x128), K split across two half-blocks
    int col = t & 127, ks2 = t >> 7;
    const float* w3p = W3 + (ks2 * 128) * 128 + col;
    const float* mp = sM2 + ks2 * 128;
    float o = 0.f;
#pragma unroll 8
    for (int k = 0; k < 128; k++) o = fmaf(mp[k], w3p[k * 128], o);
    sPart[t] = o;
    __syncthreads();
    if (t < 128) out[(br * 1024 + b) * 128 + t] = sPart[t] + sPart[t + 128] + b3[t];
}

// ---- launch --------------------------------------------------------------------
extern "C" void kernel_launch(void* const* d_in, const int* in_sizes, int n_in,
                              void* d_out, int out_size, void* d_ws, size_t ws_size,
                              hipStream_t stream) {
    const float* img = (const float*)d_in[0];
    const float* tn  = (const float*)d_in[1];
    const float* ta  = (const float*)d_in[2];
    const float* ls  = (const float*)d_in[3];
    const float* W1  = (const float*)d_in[4];
    const float* b1  = (const float*)d_in[5];
    const float* W2  = (const float*)d_in[6];
    const float* b2  = (const float*)d_in[7];
    const float* W3  = (const float*)d_in[8];
    const float* b3  = (const float*)d_in[9];
    float* out = (float*)d_out;
    float* ws  = (float*)d_ws;

    float* e_ws = ws;                                        // 196608 f
    float* U_ws = ws + 196608;                               // 524288 f
    unsigned short* Tb  = (unsigned short*)(ws + 720896);    // 192*512 bf16
    unsigned short* W2T = (unsigned short*)(ws + 770048);    // 256*512 bf16

    prep_kernel<<<1648, 256, 0, stream>>>(img, tn, ta, ls, W1, W2, e_ws, U_ws, Tb, W2T);
    branch_mlp3<<<dim3(1024, 2), 256, 0, stream>>>(U_ws, Tb, e_ws, W2T, b1, b2, W3, b3, out);
}

// Round 4
// 205.979 us; speedup vs baseline: 1.5794x; 1.5794x over previous
//
#include <hip/hip_runtime.h>
#include <hip/hip_bf16.h>

// B=1024, N=96/branch, D=512.
// h1[b,n,:] = relu(U[b] + e[b,n]*T[n] + b1);  U=img@W1[:512], T=text@W1[512:]
// m2[b] = mean_n relu(h1@W2 + b2);  out = m2@W3 + b3
// prep (round-2 version): sims/softmax/e + U gemm + T gemm (bf16) + W2^T bf16.
// branch_mlp4: double-buffered sH, ONE barrier per 64-K tile, T+W2T reg prefetch.

typedef __attribute__((ext_vector_type(8))) short short8;
typedef __attribute__((ext_vector_type(4))) float floatx4;
typedef __attribute__((ext_vector_type(4))) unsigned int uint4v;

__device__ __forceinline__ unsigned short f2bf(float x) {
    unsigned int u = __float_as_uint(x);
    u += 0x7fffu + ((u >> 16) & 1u);   // RNE
    return (unsigned short)(u >> 16);
}
__device__ __forceinline__ float bf2f(unsigned short u) {
    return __uint_as_float(((unsigned int)u) << 16);
}

// ---------------- 64x64-tile fp32 GEMM body (K=512) -----------------------------
template <bool BF16OUT>
__device__ __forceinline__ void gemm64(
    const float* __restrict__ A0, const float* __restrict__ A1, int rows0,
    const float* __restrict__ Bm, float* __restrict__ Cf,
    unsigned short* __restrict__ Cb, int bx, int by,
    unsigned char* smem, int t) {
    float (*sAT)[68] = (float (*)[68])smem;   // [kk][row]
    int r0b = bx * 64, c0b = by * 64;
    int rg = t >> 4, cg = t & 15;
    int c0 = c0b + cg * 4;
    float acc[4][4];
#pragma unroll
    for (int r = 0; r < 4; r++)
#pragma unroll
        for (int c = 0; c < 4; c++) acc[r][c] = 0.f;

    for (int k0 = 0; k0 < 512; k0 += 32) {
#pragma unroll
        for (int i = 0; i < 2; i++) {
            int row = (t >> 3) + i * 32;
            int kk = (t & 7) * 4;
            int gr = r0b + row;
            const float* Ap = (gr < rows0) ? (A0 + gr * 512) : (A1 + (gr - rows0) * 512);
            float4 av = *(const float4*)(Ap + k0 + kk);
            sAT[kk + 0][row] = av.x; sAT[kk + 1][row] = av.y;
            sAT[kk + 2][row] = av.z; sAT[kk + 3][row] = av.w;
        }
        __syncthreads();
#pragma unroll
        for (int kk = 0; kk < 32; kk++) {
            float4 a = *(const float4*)(&sAT[kk][rg * 4]);
            float4 bv = *(const float4*)(Bm + (k0 + kk) * 512 + c0);
            float ar[4] = {a.x, a.y, a.z, a.w};
            float bc[4] = {bv.x, bv.y, bv.z, bv.w};
#pragma unroll
            for (int r = 0; r < 4; r++)
#pragma unroll
                for (int c = 0; c < 4; c++)
                    acc[r][c] = fmaf(ar[r], bc[c], acc[r][c]);
        }
        __syncthreads();
    }
    int r0 = r0b + rg * 4;
#pragma unroll
    for (int r = 0; r < 4; r++) {
        if (BF16OUT) {
            unsigned long long pk =
                (unsigned long long)f2bf(acc[r][0]) |
                ((unsigned long long)f2bf(acc[r][1]) << 16) |
                ((unsigned long long)f2bf(acc[r][2]) << 32) |
                ((unsigned long long)f2bf(acc[r][3]) << 48);
            *(unsigned long long*)(Cb + (r0 + r) * 512 + c0) = pk;
        } else {
            *(float4*)(Cf + (r0 + r) * 512 + c0) =
                make_float4(acc[r][0], acc[r][1], acc[r][2], acc[r][3]);
        }
    }
}

// ---------------- prep (round-2 layout) -----------------------------------------
// [0,1024): sims+softmax+e | [1024,1152): U gemm | [1152,1176): T gemm(bf16)
// [1176,1180): W2 -> W2T bf16
__global__ __launch_bounds__(256) void prep_kernel(
    const float* __restrict__ img, const float* __restrict__ tn,
    const float* __restrict__ ta, const float* __restrict__ ls,
    const float* __restrict__ W1, const float* __restrict__ W2,
    float* __restrict__ e_ws, float* __restrict__ U_ws,
    unsigned short* __restrict__ Tb, unsigned short* __restrict__ W2T) {
    __shared__ __align__(16) unsigned char smem[9216];
    int idx = blockIdx.x;
    int t = threadIdx.x;

    if (idx < 1024) {
        int b = idx;
        float* sImg = (float*)smem;          // 512
        float* sS   = sImg + 512;            // 192
        float* sMx  = sS + 192;              // 2
        float* sSum = sMx + 2;               // 2
        for (int i = t; i < 512; i += 256) sImg[i] = img[b * 512 + i];
        __syncthreads();
        float scale = __expf(ls[0]);
        int g = t & 7;
#pragma unroll
        for (int i = 0; i < 6; i++) {
            int n = (t >> 3) + 32 * i;       // 0..191
            const float* tx = (n < 96) ? (tn + n * 512) : (ta + (n - 96) * 512);
            float d = 0.f;
#pragma unroll
            for (int s = 0; s < 16; s++) {
                int k = g * 4 + s * 32;
                float4 x = *(const float4*)(tx + k);
                d += x.x * sImg[k] + x.y * sImg[k + 1] + x.z * sImg[k + 2] + x.w * sImg[k + 3];
            }
            d += __shfl_xor(d, 1);
            d += __shfl_xor(d, 2);
            d += __shfl_xor(d, 4);
            if (g == 0) sS[n] = d * scale;
        }
        __syncthreads();
        if (t < 2) {
            float m = -1e30f;
            for (int n = 0; n < 96; n++) m = fmaxf(m, sS[t * 96 + n]);
            float s = 0.f;
            for (int n = 0; n < 96; n++) s += __expf(sS[t * 96 + n] - m);
            sMx[t] = m; sSum[t] = s;
        }
        __syncthreads();
        if (t < 192) {
            int br = t / 96, n = t % 96;
            float w = __expf(sS[t] - sMx[br]) / sSum[br];
            e_ws[(br * 1024 + b) * 96 + n] = __expf(w);
        }
    } else if (idx < 1152) {
        int i = idx - 1024;
        gemm64<false>(img, img, 1 << 20, W1, U_ws, nullptr, i & 15, i >> 4, smem, t);
    } else if (idx < 1176) {
        int i = idx - 1152;
        gemm64<true>(tn, ta, 96, W1 + 512 * 512, nullptr, Tb, i % 3, i / 3, smem, t);
    } else {
        int i = idx - 1176;
        int n0 = i * 64;
        for (int r = 0; r < 64; r++) {
            int n = n0 + r;
            for (int k = t; k < 512; k += 256)
                W2T[n * 512 + k] = f2bf(W2[k * 256 + n]);
        }
    }
}

// ---------------- branch_mlp4: dbuf sH, 1 barrier/tile, reg prefetch ------------
// grid (1024, 2), block 256 (4 waves). Rows 96, cols 256, K=512, BK=64.
__global__ __launch_bounds__(256, 2) void branch_mlp4(
    const float* __restrict__ U, const unsigned short* __restrict__ Tb,
    const float* __restrict__ e_all, const unsigned short* __restrict__ W2T,
    const float* __restrict__ b1, const float* __restrict__ b2,
    const float* __restrict__ W3, const float* __restrict__ b3,
    float* __restrict__ out) {
    int b = blockIdx.x, br = blockIdx.y;
    const unsigned short* T = Tb + br * (96 * 512);

    __shared__ float sUb[512];
    __shared__ float sE[96];
    __shared__ __align__(16) unsigned short sH[2][96][88];
    __shared__ float sM2[256];
    __shared__ float sPart[256];

    int t = threadIdx.x;
    for (int i = t; i < 512; i += 256) sUb[i] = U[b * 512 + i] + b1[i];
    if (t < 96) sE[t] = e_all[(br * 1024 + b) * 96 + t];
    __syncthreads();

    const int wave = t >> 6, lane = t & 63;
    const int frow = lane & 15, fkq = (lane >> 4) * 8;
    const int ncol0 = wave * 64;
    const int srow = t >> 3;          // 0..31
    const int skc = (t & 7) * 8;      // 0..56

    const floatx4 fz = {0.f, 0.f, 0.f, 0.f};
    floatx4 acc[6][4];
#pragma unroll
    for (int mt = 0; mt < 6; mt++)
#pragma unroll
        for (int j = 0; j < 4; j++) acc[mt][j] = fz;

    // staging-row constants + tile-0 prefetch
    int trow[3]; float ev[3]; short8 tv[3];
#pragma unroll
    for (int i2 = 0; i2 < 3; i2++) {
        trow[i2] = srow + 32 * i2;
        ev[i2] = sE[trow[i2]];
        tv[i2] = *(const short8*)(T + trow[i2] * 512 + skc);
    }
    // W2T ks=0 fragments for tile 0 (prefetched); ks=1 loaded just-in-time
    const unsigned short* Bbase = W2T + (ncol0 + frow) * 512 + fkq;
    short8 bpre[4];
#pragma unroll
    for (int j = 0; j < 4; j++)
        bpre[j] = *(const short8*)(Bbase + j * (16 * 512));

#pragma unroll
    for (int s = 0; s < 8; s++) {
        int k0 = s * 64;
        // ---- stage tile s into sH[s&1] from tv regs ----
        float4 u0 = *(const float4*)(&sUb[k0 + skc]);
        float4 u1 = *(const float4*)(&sUb[k0 + skc + 4]);
        float ua[8] = {u0.x, u0.y, u0.z, u0.w, u1.x, u1.y, u1.z, u1.w};
#pragma unroll
        for (int i2 = 0; i2 < 3; i2++) {
            uint4v pk;
#pragma unroll
            for (int jj = 0; jj < 4; jj++) {
                float f0 = fmaxf(fmaf(ev[i2], bf2f((unsigned short)tv[i2][2 * jj]), ua[2 * jj]), 0.f);
                float f1 = fmaxf(fmaf(ev[i2], bf2f((unsigned short)tv[i2][2 * jj + 1]), ua[2 * jj + 1]), 0.f);
                __hip_bfloat162 h2 = __float22bfloat162_rn(make_float2(f0, f1));
                unsigned int bits;
                __builtin_memcpy(&bits, &h2, 4);
                pk[jj] = bits;
            }
            *(uint4v*)(&sH[s & 1][trow[i2]][skc]) = pk;
        }
        // ---- prefetch tile s+1 (T rows + W2T ks=0) before the barrier ----
        short8 bcur0[4];
#pragma unroll
        for (int j = 0; j < 4; j++) bcur0[j] = bpre[j];
        if (s < 7) {
#pragma unroll
            for (int i2 = 0; i2 < 3; i2++)
                tv[i2] = *(const short8*)(T + trow[i2] * 512 + k0 + 64 + skc);
#pragma unroll
            for (int j = 0; j < 4; j++)
                bpre[j] = *(const short8*)(Bbase + j * (16 * 512) + k0 + 64);
        }
        __syncthreads();
        // ---- MFMA tile s: ks=0 with prefetched frags; ks=1 JIT (hidden) ----
        short8 b1f[4];
#pragma unroll
        for (int j = 0; j < 4; j++)
            b1f[j] = *(const short8*)(Bbase + j * (16 * 512) + k0 + 32);
#pragma unroll
        for (int mt = 0; mt < 6; mt++) {
            short8 afr = *(const short8*)(&sH[s & 1][mt * 16 + frow][fkq]);
#pragma unroll
            for (int j = 0; j < 4; j++)
                acc[mt][j] = __builtin_amdgcn_mfma_f32_16x16x32_bf16(afr, bcur0[j], acc[mt][j], 0, 0, 0);
        }
#pragma unroll
        for (int mt = 0; mt < 6; mt++) {
            short8 afr = *(const short8*)(&sH[s & 1][mt * 16 + frow][32 + fkq]);
#pragma unroll
            for (int j = 0; j < 4; j++)
                acc[mt][j] = __builtin_amdgcn_mfma_f32_16x16x32_bf16(afr, b1f[j], acc[mt][j], 0, 0, 0);
        }
    }

    // epilogue 1: +b2, relu, mean over 96 rows -> sM2[256]
#pragma unroll
    for (int j = 0; j < 4; j++) {
        int col = ncol0 + j * 16 + frow;
        float bb = b2[col];
        float s = 0.f;
#pragma unroll
        for (int mt = 0; mt < 6; mt++)
#pragma unroll
            for (int r = 0; r < 4; r++)
                s += fmaxf(acc[mt][j][r] + bb, 0.f);
        s += __shfl_xor(s, 16);
        s += __shfl_xor(s, 32);
        if (lane < 16) sM2[col] = s * (1.0f / 96.0f);
    }
    __syncthreads();

    // epilogue 2: out = sM2 @ W3 + b3   (256x128), K split across two half-blocks
    int col = t & 127, ks2 = t >> 7;
    const float* w3p = W3 + (ks2 * 128) * 128 + col;
    const float* mp = sM2 + ks2 * 128;
    float o = 0.f;
#pragma unroll 8
    for (int k = 0; k < 128; k++) o = fmaf(mp[k], w3p[k * 128], o);
    sPart[t] = o;
    __syncthreads();
    if (t < 128) out[(br * 1024 + b) * 128 + t] = sPart[t] + sPart[t + 128] + b3[t];
}

// ---------------- launch --------------------------------------------------------
extern "C" void kernel_launch(void* const* d_in, const int* in_sizes, int n_in,
                              void* d_out, int out_size, void* d_ws, size_t ws_size,
                              hipStream_t stream) {
    const float* img = (const float*)d_in[0];
    const float* tn  = (const float*)d_in[1];
    const float* ta  = (const float*)d_in[2];
    const float* ls  = (const float*)d_in[3];
    const float* W1  = (const float*)d_in[4];
    const float* b1  = (const float*)d_in[5];
    const float* W2  = (const float*)d_in[6];
    const float* b2  = (const float*)d_in[7];
    const float* W3  = (const float*)d_in[8];
    const float* b3  = (const float*)d_in[9];
    float* out = (float*)d_out;
    float* ws  = (float*)d_ws;

    float* e_ws = ws;                                        // 196608 f
    float* U_ws = ws + 196608;                               // 524288 f
    unsigned short* Tb  = (unsigned short*)(ws + 720896);    // 192*512 bf16
    unsigned short* W2T = (unsigned short*)(ws + 770048);    // 256*512 bf16

    prep_kernel<<<1180, 256, 0, stream>>>(img, tn, ta, ls, W1, W2, e_ws, U_ws, Tb, W2T);
    branch_mlp4<<<dim3(1024, 2), 256, 0, stream>>>(U_ws, Tb, e_ws, W2T, b1, b2, W3, b3, out);
}